// Round 3
// baseline (247.470 us; speedup 1.0000x reference)
//
#include <hip/hip_runtime.h>

#define B_DIM 4
#define T_DIM 96
#define N_DIM 512
#define H_DIM 128
#define NH    (N_DIM * H_DIM)

// d_ws layout (in bf16 shorts):
#define WS_WEXP  0        // [256][128] bf16 row-major
#define WS_WCON  32768    // [128][128] bf16 row-major
#define WS_L     49152    // [96][96]  bf16 row-major: L[t][k] = 0.1*0.9^(t-k), k<=t
#define WS_TOTAL 58368

typedef __attribute__((ext_vector_type(8))) short short8;
typedef __attribute__((ext_vector_type(4))) float f32x4;

__device__ __forceinline__ unsigned short f2b_rh(float f) {
    union { float f; unsigned u; } c; c.f = f;
    return (unsigned short)((c.u + 0x8000u) >> 16);   // round-half-up to bf16
}
// pack two fp32 -> bf16x2 (low = a, high = b): 2 adds + 1 v_perm_b32
__device__ __forceinline__ unsigned pack_bf16_2(float a, float b) {
    union { float f; unsigned u; } ca, cb; ca.f = a; cb.f = b;
    return __builtin_amdgcn_perm(cb.u + 0x8000u, ca.u + 0x8000u, 0x07060302u);
}
__device__ __forceinline__ float b2f(unsigned short s) {
    union { unsigned u; float f; } c; c.u = ((unsigned)s) << 16;
    return c.f;
}

// ---- Prep: fp32 weights -> bf16 in ws; build EMA coefficient matrix L ----
extern "C" __global__ void prep_kernel(const float* __restrict__ Wexp,
                                       const float* __restrict__ Wcon,
                                       unsigned short* __restrict__ ws) {
    int i = blockIdx.x * 256 + threadIdx.x;
    if (i < 32768) {
        ws[WS_WEXP + i] = f2b_rh(Wexp[i]);
    } else if (i < 49152) {
        int j = i - 32768;
        ws[WS_WCON + j] = f2b_rh(Wcon[j]);
    } else if (i < WS_TOTAL) {
        int j = i - 49152;
        int t = j / 96, k = j - t * 96;
        float v = 0.0f;
        if (k <= t) v = 0.1f * __expf((float)(t - k) * -0.1053605157f); // 0.1*0.9^(t-k)
        ws[WS_L + j] = f2b_rh(v);
    }
}

// One workgroup per (b, n). Wave w owns feature rows h in [32w, 32w+32):
//   GEMM1 -> prim tiles (registers) + gate tiles (LDS, transposed, OWN slice only)
//   EMA = G^T x L^T via MFMA (triangular-skipped)   [no barrier before: wave-local]
//   sigmoid * prim in registers -> pg [t][h] in LDS (aliases gateT; barrier protects)
//   GEMM2 -> out fp32
// MFMA 16x16x32 bf16 layouts (verified rounds 1-2):
//   A[m=l16][k=q*8+j], B[k=q*8+j][n=l16], D[row=q*4+r][col=l16]
extern "C" __global__ __launch_bounds__(256, 4)
void mamba_fused(const float* __restrict__ x,
                 const unsigned short* __restrict__ ws,
                 const float* __restrict__ b_exp,
                 const float* __restrict__ b_con,
                 float* __restrict__ out)
{
    // union buffer: gateT[h][t'] stride 104 (128*104=13312); pg[t][h] stride 136 (96*136=13056)
    __shared__ __align__(16) unsigned short smem[13312];

    const int tid  = threadIdx.x;
    const int wave = tid >> 6;
    const int lane = tid & 63;
    const int q    = lane >> 4;
    const int l16  = lane & 15;

    const int blk = blockIdx.x;
    const int n   = blk & (N_DIM - 1);
    const int b   = blk >> 9;

    const float* xg = x + ((size_t)b * T_DIM * N_DIM + (size_t)n) * H_DIM;

    // ---- W_exp A-fragments: ot 0,1 -> prim rows [32w,32w+32); ot 2,3 -> gate rows +128 ----
    short8 wf[4][4];
    float4 bias1[4];
    {
        const unsigned short* wsW = ws + WS_WEXP;
        for (int ot = 0; ot < 4; ++ot) {
            const int orow = (ot < 2) ? (wave * 32 + ot * 16)
                                      : (128 + wave * 32 + (ot - 2) * 16);
            const unsigned short* wrow = wsW + (size_t)(orow + l16) * H_DIM + q * 8;
            for (int k0 = 0; k0 < 4; ++k0)
                wf[ot][k0] = *(const short8*)(wrow + k0 * 32);
            bias1[ot] = *(const float4*)(b_exp + orow + q * 4);
        }
    }

    // ---- GEMM1: x B-frags from global; prim -> registers, gate -> LDS (own slice) ----
    ushort4 primf[2][6];
    for (int mt = 0; mt < 6; ++mt) {
        const float* xrow = xg + (size_t)(mt * 16 + l16) * NH + q * 8;
        short8 bfr[4];
        for (int k0 = 0; k0 < 4; ++k0) {
            float4 v0 = *(const float4*)(xrow + k0 * 32);
            float4 v1 = *(const float4*)(xrow + k0 * 32 + 4);
            union { unsigned u[4]; short8 s; } p;
            p.u[0] = pack_bf16_2(v0.x, v0.y);
            p.u[1] = pack_bf16_2(v0.z, v0.w);
            p.u[2] = pack_bf16_2(v1.x, v1.y);
            p.u[3] = pack_bf16_2(v1.z, v1.w);
            bfr[k0] = p.s;
        }
        const int tcol = mt * 16 + l16;
        for (int ot = 0; ot < 4; ++ot) {
            f32x4 acc = {0.f, 0.f, 0.f, 0.f};
            for (int k0 = 0; k0 < 4; ++k0)
                acc = __builtin_amdgcn_mfma_f32_16x16x32_bf16(wf[ot][k0], bfr[k0], acc, 0, 0, 0);
            float r0 = acc[0] + bias1[ot].x, r1 = acc[1] + bias1[ot].y;
            float r2 = acc[2] + bias1[ot].z, r3 = acc[3] + bias1[ot].w;
            if (ot < 2) {                          // prim: keep in registers (bf16 packed)
                union { unsigned u[2]; ushort4 s; } pk;
                pk.u[0] = pack_bf16_2(r0, r1);
                pk.u[1] = pack_bf16_2(r2, r3);
                primf[ot][mt] = pk.s;
            } else {                               // gate: transpose into own LDS slice
                const int g0 = wave * 32 + (ot - 2) * 16 + q * 4;
                smem[(g0 + 0) * 104 + tcol] = f2b_rh(r0);
                smem[(g0 + 1) * 104 + tcol] = f2b_rh(r1);
                smem[(g0 + 2) * 104 + tcol] = f2b_rh(r2);
                smem[(g0 + 3) * 104 + tcol] = f2b_rh(r3);
            }
        }
    }

    // ---- EMA A-frags from OWN gateT slice (wave-local: no barrier needed) ----
    short8 afr[2][3];
    for (int ht = 0; ht < 2; ++ht) {
        const int h = (wave * 2 + ht) * 16 + l16;
        for (int kf = 0; kf < 3; ++kf)
            afr[ht][kf] = *(const short8*)&smem[h * 104 + kf * 32 + q * 8];
    }
    __syncthreads();   // all gateT reads done before pg overwrites the buffer

    // ---- EMA via MFMA: S^T[h][t] = sum_t' G^T[h][t'] L[t][t'], triangular-skipped ----
    f32x4 eacc[2][6];
    for (int ht = 0; ht < 2; ++ht)
        for (int tt = 0; tt < 6; ++tt)
            eacc[ht][tt] = (f32x4){0.f, 0.f, 0.f, 0.f};
    {
        const unsigned short* wsL = ws + WS_L;
        for (int kf = 0; kf < 3; ++kf) {
            for (int tt = 2 * kf; tt < 6; ++tt) {   // tiles with kf*32 > tt*16+15 are all-zero
                short8 bf = *(const short8*)(wsL + (size_t)(tt * 16 + l16) * 96 + kf * 32 + q * 8);
                eacc[0][tt] = __builtin_amdgcn_mfma_f32_16x16x32_bf16(afr[0][kf], bf, eacc[0][tt], 0, 0, 0);
                eacc[1][tt] = __builtin_amdgcn_mfma_f32_16x16x32_bf16(afr[1][kf], bf, eacc[1][tt], 0, 0, 0);
            }
        }
    }

    // ---- sigmoid(EMA) * prim (registers) -> pg [t][h] stride 136 ----
    for (int ht = 0; ht < 2; ++ht) {
        const int hb = wave * 32 + ht * 16 + q * 4;
        for (int tt = 0; tt < 6; ++tt) {
            const int t = tt * 16 + l16;
            f32x4 s = eacc[ht][tt];
            float sg0 = __fdividef(1.f, 1.f + __expf(-s[0]));
            float sg1 = __fdividef(1.f, 1.f + __expf(-s[1]));
            float sg2 = __fdividef(1.f, 1.f + __expf(-s[2]));
            float sg3 = __fdividef(1.f, 1.f + __expf(-s[3]));
            ushort4 pv = primf[ht][tt];
            float p0 = b2f(pv.x) * sg0, p1 = b2f(pv.y) * sg1;
            float p2 = b2f(pv.z) * sg2, p3 = b2f(pv.w) * sg3;
            union { unsigned u[2]; ushort4 s; } pk;
            pk.u[0] = pack_bf16_2(p0, p1);
            pk.u[1] = pack_bf16_2(p2, p3);
            *(ushort4*)&smem[t * 136 + hb] = pk.s;
        }
    }
    __syncthreads();

    // ---- GEMM2: out[o][t] = Wc @ pg^T + b ----
    short8 wc[2][4];
    float4 bias2[2];
    {
        const unsigned short* wsW = ws + WS_WCON;
        for (int ot = 0; ot < 2; ++ot) {
            const unsigned short* wrow = wsW + (size_t)(wave * 32 + ot * 16 + l16) * H_DIM + q * 8;
            for (int k0 = 0; k0 < 4; ++k0)
                wc[ot][k0] = *(const short8*)(wrow + k0 * 32);
            bias2[ot] = *(const float4*)(b_con + wave * 32 + ot * 16 + q * 4);
        }
    }
    float* og = out + ((size_t)b * T_DIM * N_DIM + (size_t)n) * H_DIM;
    for (int mt = 0; mt < 6; ++mt) {
        short8 bfr[4];
        const unsigned short* prow = &smem[(mt * 16 + l16) * 136];
        for (int k0 = 0; k0 < 4; ++k0)
            bfr[k0] = *(const short8*)(prow + k0 * 32 + q * 8);
        const int t = mt * 16 + l16;
        for (int ot = 0; ot < 2; ++ot) {
            f32x4 acc = {0.f, 0.f, 0.f, 0.f};
            for (int k0 = 0; k0 < 4; ++k0)
                acc = __builtin_amdgcn_mfma_f32_16x16x32_bf16(wc[ot][k0], bfr[k0], acc, 0, 0, 0);
            const int o = wave * 32 + ot * 16 + q * 4;
            float4 v;
            v.x = acc[0] + bias2[ot].x;
            v.y = acc[1] + bias2[ot].y;
            v.z = acc[2] + bias2[ot].z;
            v.w = acc[3] + bias2[ot].w;
            *(float4*)(og + (size_t)t * NH + o) = v;
        }
    }
}

extern "C" void kernel_launch(void* const* d_in, const int* in_sizes, int n_in,
                              void* d_out, int out_size, void* d_ws, size_t ws_size,
                              hipStream_t stream) {
    const float* x     = (const float*)d_in[0];
    const float* W_exp = (const float*)d_in[1];
    const float* b_exp = (const float*)d_in[2];
    const float* W_con = (const float*)d_in[3];
    const float* b_con = (const float*)d_in[4];
    float* out = (float*)d_out;
    unsigned short* ws = (unsigned short*)d_ws;

    hipLaunchKernelGGL(prep_kernel, dim3(WS_TOTAL / 256), dim3(256), 0, stream,
                       W_exp, W_con, ws);
    hipLaunchKernelGGL(mamba_fused, dim3(B_DIM * N_DIM), dim3(256), 0, stream,
                       x, ws, b_exp, b_con, out);
}